// Round 11
// baseline (342.187 us; speedup 1.0000x reference)
//
#include <hip/hip_runtime.h>
#include <hip/hip_bf16.h>
#include <cstdint>
#include <cstddef>

#define B_ 4
#define L_ 2048
#define C_ 1024
#define H_ 16
#define D_ 64

typedef __bf16    bf16x2 __attribute__((ext_vector_type(2)));
typedef __bf16    bf16x4 __attribute__((ext_vector_type(4)));
typedef __bf16    bf16x8 __attribute__((ext_vector_type(8)));
typedef _Float16  f16x4  __attribute__((ext_vector_type(4)));
typedef _Float16  f16x8  __attribute__((ext_vector_type(8)));
typedef float     f32x4  __attribute__((ext_vector_type(4)));
typedef float     f32x16 __attribute__((ext_vector_type(16)));
typedef uint32_t  u32x4  __attribute__((ext_vector_type(4)));

// async global->LDS, 16 B per lane. LDS dest = wave-uniform base + lane*16.
typedef const __attribute__((address_space(1))) uint32_t* gas_ptr;
typedef __attribute__((address_space(3))) uint32_t* las_ptr;
__device__ __forceinline__ void gl_lds16(const void* g, void* l) {
    __builtin_amdgcn_global_load_lds((gas_ptr)(uintptr_t)g,
                                     (las_ptr)(uintptr_t)l, 16, 0, 0);
}

// v_cvt_pk_bf16_f32: pack 2 f32 -> u32 of 2 bf16 (no builtin on gfx950, m240)
__device__ __forceinline__ uint32_t cvtpk_bf16(float lo, float hi) {
    uint32_t r;
    asm("v_cvt_pk_bf16_f32 %0, %1, %2" : "=v"(r) : "v"(lo), "v"(hi));
    return r;
}
// v_permlane32_swap_b32: a.hi <-> b.lo (VALU cross-lane, no LDS pipe)
__device__ __forceinline__ void plswap(uint32_t& a, uint32_t& b) {
    asm("v_permlane32_swap_b32 %0, %1" : "+v"(a), "+v"(b));
}

// ---------------------------------------------------------------------------
// prep kernel: region A = x fp32->fp16 (8192 blocks), region B = Wqkv
// transpose+cvt (768 blocks), region C = Wout transpose+cvt (256 blocks).
// ---------------------------------------------------------------------------
__global__ __launch_bounds__(256) void prep_kernel(
    const float* __restrict__ x, _Float16* __restrict__ x16,
    const float* __restrict__ Wqkv, _Float16* __restrict__ Wq16,
    const float* __restrict__ Wout, _Float16* __restrict__ Wo16)
{
    __shared__ float tile[64][65];
    int bid = blockIdx.x;
    const int tid = threadIdx.x;

    if (bid < 8192) {                      // cvt x
        int i = (bid * 256 + tid) * 4;
        float4 v = *(const float4*)&x[i];
        f16x4 o = {(_Float16)v.x, (_Float16)v.y, (_Float16)v.z, (_Float16)v.w};
        *(f16x4*)&x16[i] = o;
        return;
    }
    bid -= 8192;
    const float* W; _Float16* Wt; int N, tx, ty;
    if (bid < 768) { W = Wqkv; Wt = Wq16; N = 3072; tx = bid % 48; ty = bid / 48; }
    else { bid -= 768; W = Wout; Wt = Wo16; N = 1024; tx = bid % 16; ty = bid / 16; }
    const int K = 1024;
    const int k0 = ty * 64, n0 = tx * 64;
    for (int i = tid; i < 1024; i += 256) {
        int r = i >> 4, c4 = (i & 15) * 4;
        float4 v = *(const float4*)&W[(size_t)(k0 + r) * N + n0 + c4];
        tile[r][c4 + 0] = v.x; tile[r][c4 + 1] = v.y;
        tile[r][c4 + 2] = v.z; tile[r][c4 + 3] = v.w;
    }
    __syncthreads();
    for (int i = tid; i < 1024; i += 256) {
        int n = i >> 4, k4 = (i & 15) * 4;
        f16x4 o = {(_Float16)tile[k4 + 0][n], (_Float16)tile[k4 + 1][n],
                   (_Float16)tile[k4 + 2][n], (_Float16)tile[k4 + 3][n]};
        *(f16x4*)&Wt[(size_t)(n0 + n) * K + k0 + k4] = o;
    }
}

// ---------------------------------------------------------------------------
// fp16 MFMA GEMM. R10 change: B-operand DIRECT from global, register
// double-buffered (theory: kernel is LDS-pipe-bound — 16 b128 reads +
// 6 gl_lds writes per wave-iter vs ~640cy MFMA; B-direct removes 8 reads
// + 2 writes = ~45% of LDS traffic). B = weights -> same panel read by all
// blocks of a grid column -> L2-hot; reload of br[h] issued AFTER its MFMAs
// (SSA lets the scheduler hoist) and consumed one full k-iter later.
//  - A staging unchanged: BK=64, XOR chunk-swizzle (R7/R8-proven).
//  - LDS = Ash only, 16 KB. VGPR ~116 expected (<=128 bin, 4 waves/SIMD).
//  - MODE 1 (QKV): 128x128, 256 thr. MODE 0 (out-proj): 128x64, 256 thr.
// R9 lesson kept: no launch-bounds occupancy hints that squeeze VGPR.
// ---------------------------------------------------------------------------
template <int MODE>
__global__ __launch_bounds__(256) void gemm_f16_bt_kernel(
    const _Float16* __restrict__ A, const _Float16* __restrict__ Bt,
    const float* __restrict__ bias, void* __restrict__ Cout,
    __bf16* __restrict__ vTout, const float* __restrict__ q_gamma,
    const float* __restrict__ k_gamma, int M, int N, int K)
{
    constexpr int BN = (MODE == 0) ? 64 : 128;   // cols per block
    constexpr int NJ = BN / 32;                  // acc cols per wave (2 or 4)
    __shared__ __align__(16) char smraw[128 * 64 * 2];   // A tile only, 16 KB
    _Float16* Ash = (_Float16*)smraw;

    const int tid  = threadIdx.x;
    const int lane = tid & 63;
    const int wv   = tid >> 6;
    const int wm   = wv & 1, wn = wv >> 1;
    const int n16  = lane & 15, quad = lane >> 4;
    const int brow = blockIdx.y * 128;
    const int bcol = blockIdx.x * BN;

    // A staging: 8 rows/call, 8 x 16B chunks/row; lane -> row rr = lane>>3,
    // chunk pos cc = lane&7, SOURCE chunk cc^rr (inverse swizzle).
    const int rr = lane >> 3;
    const int sw = ((lane & 7) ^ rr) * 8;        // source k-offset (elems)
    const _Float16* gA = A + (size_t)(brow + wv * 32 + rr) * K + sw;
    _Float16* lA = &Ash[(wv * 32) * 64];

    // B direct-from-global fragment base: row = bcol + wn*(BN/2) + j*16 + n16,
    // k-offset = k0 + h*32 + quad*8.
    const _Float16* gBf = Bt + (size_t)(bcol + wn * (BN / 2) + n16) * K + quad * 8;

    f32x4 acc[4][NJ] = {};

    // prime both half-buffers for k0 = 0
    f16x8 br0[NJ], br1[NJ];
    #pragma unroll
    for (int j = 0; j < NJ; j++) {
        br0[j] = *(const f16x8*)&gBf[(size_t)j * 16 * K];
        br1[j] = *(const f16x8*)&gBf[(size_t)j * 16 * K + 32];
    }

    for (int k0 = 0; k0 < K; k0 += 64) {
        #pragma unroll
        for (int t = 0; t < 4; t++)
            gl_lds16(gA + k0 + (size_t)t * 8 * K, lA + t * 8 * 64);
        __syncthreads();

        #pragma unroll
        for (int h = 0; h < 2; h++) {
            f16x8 ar[4];
            #pragma unroll
            for (int t = 0; t < 4; t++) {
                const int row = wm * 64 + t * 16 + n16;
                ar[t] = *(const f16x8*)&Ash[row * 64 + (((h << 2) | quad) ^ (row & 7)) * 8];
            }
            f16x8* cur = h ? br1 : br0;
            #pragma unroll
            for (int i = 0; i < 4; i++)
                #pragma unroll
                for (int j = 0; j < NJ; j++)
                    acc[i][j] = __builtin_amdgcn_mfma_f32_16x16x32_f16(
                        ar[i], cur[j], acc[i][j], 0, 0, 0);
            // refill this half's buffer with next k-iter's fragments
            if (k0 + 64 < K) {
                #pragma unroll
                for (int j = 0; j < NJ; j++)
                    cur[j] = *(const f16x8*)&gBf[(size_t)j * 16 * K + k0 + 64 + h * 32];
            }
        }
        __syncthreads();
    }

    if (MODE == 0) {
        #pragma unroll
        for (int j = 0; j < NJ; j++) {
            const int col = bcol + wn * (BN / 2) + j * 16 + n16;
            const float bv = bias[col];
            #pragma unroll
            for (int i = 0; i < 4; i++) {
                const int row0 = brow + wm * 64 + i * 16 + quad * 4;
                #pragma unroll
                for (int r = 0; r < 4; r++)
                    ((float*)Cout)[(size_t)(row0 + r) * N + col] = acc[i][j][r] + bv;
            }
        }
        return;
    }

    // ---------------- MODE 1: fused QKV epilogue ----------------
    const int region = bcol >> 10;         // 0 = q, 1 = k, 2 = v
    float bj[4];
    #pragma unroll
    for (int j = 0; j < 4; j++) bj[j] = bias[bcol + wn * 64 + j * 16 + n16];

    if (region < 2) {
        const float* gamma = (region == 0) ? q_gamma : k_gamma;
        const float scl = (region == 0) ? 1.44269504f : 8.0f;  // log2e | sqrt(D)
        const int cb = (bcol & 1023) + wn * 64 + n16;          // head-local col
        float gj[4];
        #pragma unroll
        for (int j = 0; j < 4; j++) gj[j] = gamma[cb + j * 16];

        #pragma unroll
        for (int i = 0; i < 4; i++) {
            #pragma unroll
            for (int r = 0; r < 4; r++) {
                float v0 = acc[i][0][r] + bj[0];
                float v1 = acc[i][1][r] + bj[1];
                float v2 = acc[i][2][r] + bj[2];
                float v3 = acc[i][3][r] + bj[3];
                float ss = v0 * v0 + v1 * v1 + v2 * v2 + v3 * v3;
                ss += __shfl_xor(ss, 1, 64);
                ss += __shfl_xor(ss, 2, 64);
                ss += __shfl_xor(ss, 4, 64);
                ss += __shfl_xor(ss, 8, 64);
                const float sc = scl / fmaxf(sqrtf(ss), 1e-12f);
                const int row = brow + wm * 64 + i * 16 + quad * 4 + r;
                __bf16* op = (__bf16*)Cout + (size_t)row * 3072 + bcol + wn * 64 + n16;
                op[ 0] = (__bf16)(v0 * gj[0] * sc);
                op[16] = (__bf16)(v1 * gj[1] * sc);
                op[32] = (__bf16)(v2 * gj[2] * sc);
                op[48] = (__bf16)(v3 * gj[3] * sc);
            }
        }
    } else {
        // v region: bias + bf16, BAND transpose (4 x 32 tokens) via
        // [128][40] LDS (10240 B, aliased over Ash), store vT[b][h][d][l].
        __bf16* LTb = (__bf16*)smraw;          // [col 0..127][rowb 0..31] s=40
        const int d    = tid >> 1;             // output row (head-d), 0..127
        const int head = ((bcol - 2048) >> 6) + (d >> 6);
        const size_t vb0 = (((size_t)((brow >> 11) * 16 + head)) * 64 + (d & 63)) * 2048
                           + (brow & 2047);
        #pragma unroll
        for (int p = 0; p < 4; p++) {
            if (wm == (p >> 1)) {
                #pragma unroll
                for (int ii = 0; ii < 2; ii++) {
                    const int i = (p & 1) * 2 + ii;
                    #pragma unroll
                    for (int j = 0; j < 4; j++) {
                        const int col  = wn * 64 + j * 16 + n16;
                        const int rowb = ii * 16 + quad * 4;
                        bf16x4 t4 = {(__bf16)(acc[i][j][0] + bj[j]),
                                     (__bf16)(acc[i][j][1] + bj[j]),
                                     (__bf16)(acc[i][j][2] + bj[j]),
                                     (__bf16)(acc[i][j][3] + bj[j])};
                        *(bf16x4*)&LTb[col * 40 + rowb] = t4;
                    }
                }
            }
            __syncthreads();
            #pragma unroll
            for (int s = 0; s < 2; s++) {
                const int chunk = (tid & 1) * 2 + s;
                *(bf16x8*)&vTout[vb0 + p * 32 + chunk * 8] =
                    *(const bf16x8*)&LTb[d * 40 + chunk * 8];
            }
            __syncthreads();
        }
    }
}

// ---------------------------------------------------------------------------
// MFMA flash attention v9 (unchanged from R10 — verified, out of top-5):
// 256-q blocks, 8 waves, 32x32x16 MFMA, fully in-register P.
// ---------------------------------------------------------------------------
__global__ __launch_bounds__(512, 4) void attn_mfma_kernel(
    const __bf16* __restrict__ qkv, const __bf16* __restrict__ vT,
    _Float16* __restrict__ h16)
{
    const int tid  = threadIdx.x;
    const int lane = tid & 63;
    const int wv   = tid >> 6;           // 0..7
    const int l31  = lane & 31;
    const int h    = lane >> 5;
    const int x7   = l31 & 7;
    const int qt = blockIdx.x & 7;       // 8 q-tiles of 256
    const int hh = (blockIdx.x >> 3) & 15;
    const int bb = blockIdx.x >> 7;
    const int q0 = qt * 256;
    const int bh = bb * 16 + hh;

    __shared__ __align__(16) __bf16 smem[4 * 4096];   // 32768 B
    __bf16* Kbuf = smem;                 // 2 x [64 tok][64 d], chunk-swizzled
    __bf16* Vbuf = smem + 2 * 4096;      // 2 x [64 d][64 tok], chunk-swizzled

    const __bf16* kbase = &qkv[(size_t)(bb * L_) * 3072 + 1024 + hh * 64];
    const __bf16* vbase = &vT[(size_t)bh * 64 * 2048];

    const int lr = lane >> 3;
    const int lc = (lane & 7) ^ lr;
    const __bf16* kpre = kbase + (size_t)(wv * 8 + lr) * 3072 + lc * 8;
    const __bf16* vpre = vbase + (size_t)(wv * 8 + lr) * 2048 + lc * 8;
    __bf16* kdst = Kbuf + (wv * 8) * 64;
    __bf16* vdst = Vbuf + (wv * 8) * 64;

    gl_lds16(kpre, kdst);
    gl_lds16(vpre, vdst);

    bf16x8 qf[4];
    const __bf16* qptr = &qkv[(size_t)(bb * L_ + q0 + wv * 32 + l31) * 3072
                              + hh * 64 + h * 8];
    #pragma unroll
    for (int dk = 0; dk < 4; dk++)
        qf[dk] = *(const bf16x8*)&qptr[dk * 16];

    f32x16 acc0 = {}, acc1 = {};
    float l_run = 0.f;

    __syncthreads();   // drains K[0], V[0]

    for (int j0 = 0, cur = 0; j0 < L_; j0 += 64, cur ^= 1) {
        if (j0 + 64 < L_) {
            gl_lds16(kpre + (size_t)(j0 + 64) * 3072, kdst + (cur ^ 1) * 4096);
            gl_lds16(vpre + (j0 + 64),                vdst + (cur ^ 1) * 4096);
        }
        const __bf16* Kc = Kbuf + cur * 4096;
        const __bf16* Vc = Vbuf + cur * 4096;

        f32x16 St0 = {}, St1 = {};
        __builtin_amdgcn_s_setprio(1);
        #pragma unroll
        for (int dk = 0; dk < 4; dk++) {
            const int co = ((2 * dk + h) ^ x7) * 8;
            bf16x8 k0 = *(const bf16x8*)&Kc[l31 * 64 + co];
            bf16x8 k1 = *(const bf16x8*)&Kc[(32 + l31) * 64 + co];
            St0 = __builtin_amdgcn_mfma_f32_32x32x16_bf16(k0, qf[dk], St0, 0, 0, 0);
            St1 = __builtin_amdgcn_mfma_f32_32x32x16_bf16(k1, qf[dk], St1, 0, 0, 0);
        }
        __builtin_amdgcn_s_setprio(0);

        bf16x8 pf[4];
        float ts = 0.f;
        #pragma unroll
        for (int th = 0; th < 2; th++) {
            float e[16];
            #pragma unroll
            for (int r = 0; r < 16; r++) {
                e[r] = __builtin_amdgcn_exp2f(th == 0 ? St0[r] : St1[r]);
                ts += e[r];
            }
            uint32_t a0 = cvtpk_bf16(e[0], e[1]),  a1 = cvtpk_bf16(e[2], e[3]);
            uint32_t b0 = cvtpk_bf16(e[4], e[5]),  b1 = cvtpk_bf16(e[6], e[7]);
            plswap(a0, b0); plswap(a1, b1);
            u32x4 w0; w0.x = a0; w0.y = a1; w0.z = b0; w0.w = b1;
            pf[th * 2 + 0] = __builtin_bit_cast(bf16x8, w0);
            uint32_t c0 = cvtpk_bf16(e[8], e[9]),   c1 = cvtpk_bf16(e[10], e[11]);
            uint32_t d0 = cvtpk_bf16(e[12], e[13]), d1 = cvtpk_bf16(e[14], e[15]);
            plswap(c0, d0); plswap(c1, d1);
            u32x4 w1; w1.x = c0; w1.y = c1; w1.z = d0; w1.w = d1;
            pf[th * 2 + 1] = __builtin_bit_cast(bf16x8, w1);
        }
        l_run += ts;

        __builtin_amdgcn_s_setprio(1);
        #pragma unroll
        for (int kq = 0; kq < 4; kq++) {
            const int co = ((2 * kq + h) ^ x7) * 8;
            bf16x8 v0 = *(const bf16x8*)&Vc[l31 * 64 + co];
            bf16x8 v1 = *(const bf16x8*)&Vc[(32 + l31) * 64 + co];
            acc0 = __builtin_amdgcn_mfma_f32_32x32x16_bf16(v0, pf[kq], acc0, 0, 0, 0);
            acc1 = __builtin_amdgcn_mfma_f32_32x32x16_bf16(v1, pf[kq], acc1, 0, 0, 0);
        }
        __builtin_amdgcn_s_setprio(0);

        __syncthreads();
    }

    l_run += __shfl_xor(l_run, 32, 64);
    const float linv = 1.0f / l_run;

    const size_t orow = (size_t)(bb * L_ + q0 + wv * 32 + l31) * 1024
                        + hh * 64 + h * 4;
    #pragma unroll
    for (int m = 0; m < 4; m++) {
        f16x4 o0 = {(_Float16)(acc0[4 * m + 0] * linv),
                    (_Float16)(acc0[4 * m + 1] * linv),
                    (_Float16)(acc0[4 * m + 2] * linv),
                    (_Float16)(acc0[4 * m + 3] * linv)};
        *(f16x4*)&h16[orow + 8 * m] = o0;
        f16x4 o1 = {(_Float16)(acc1[4 * m + 0] * linv),
                    (_Float16)(acc1[4 * m + 1] * linv),
                    (_Float16)(acc1[4 * m + 2] * linv),
                    (_Float16)(acc1[4 * m + 3] * linv)};
        *(f16x4*)&h16[orow + 32 + 8 * m] = o1;
    }
}

// ---------------------------------------------------------------------------
extern "C" void kernel_launch(void* const* d_in, const int* in_sizes, int n_in,
                              void* d_out, int out_size, void* d_ws, size_t ws_size,
                              hipStream_t stream)
{
    const float* x       = (const float*)d_in[0];
    const float* Wqkv    = (const float*)d_in[1];
    const float* bqkv    = (const float*)d_in[2];
    const float* q_gamma = (const float*)d_in[3];
    const float* k_gamma = (const float*)d_in[4];
    const float* Wout    = (const float*)d_in[5];
    const float* bout    = (const float*)d_in[6];
    float* out = (float*)d_out;

    uint8_t* ws = (uint8_t*)d_ws;
    _Float16* x16   = (_Float16*)(ws);                      // 16 MB
    _Float16* Wq16  = (_Float16*)(ws + (16ull << 20));      //  6 MB
    _Float16* Wo16  = (_Float16*)(ws + (22ull << 20));      //  2 MB
    __bf16*   qkv16 = (__bf16*)  (ws + (24ull << 20));      // 48 MB (q,k used)
    _Float16* h16   = (_Float16*)(ws + (72ull << 20));      // 16 MB
    __bf16*   vT    = (__bf16*)  (ws + (88ull << 20));      // 16 MB (total 104)

    // 1) prep: x->fp16, W transposes (one launch, 3 regions)
    prep_kernel<<<8192 + 768 + 256, 256, 0, stream>>>(x, x16, Wqkv, Wq16, Wout, Wo16);

    // 2) fused QKV: GEMM (A via LDS, B direct-from-global reg-dbuf) + epilogues
    gemm_f16_bt_kernel<1><<<dim3(3 * C_ / 128, B_ * L_ / 128), 256, 0, stream>>>(
        x16, Wq16, bqkv, qkv16, vT, q_gamma, k_gamma, B_ * L_, 3 * C_, C_);

    // 3) flash attention (256-q blocks, 8 waves, 32x32 MFMA, in-reg P) -> h16
    attn_mfma_kernel<<<B_ * H_ * (L_ / 256), 512, 0, stream>>>(qkv16, vT, h16);

    // 4) out = h @ Wout + bout -> fp32 (128x64 tiles: 1024 blocks)
    gemm_f16_bt_kernel<0><<<dim3(C_ / 64, B_ * L_ / 128), 256, 0, stream>>>(
        h16, Wo16, bout, out, nullptr, nullptr, nullptr, B_ * L_, C_, C_);
}

// Round 12
// 276.914 us; speedup vs baseline: 1.2357x; 1.2357x over previous
//
#include <hip/hip_runtime.h>
#include <hip/hip_bf16.h>
#include <cstdint>
#include <cstddef>

#define B_ 4
#define L_ 2048
#define C_ 1024
#define H_ 16
#define D_ 64

typedef __bf16    bf16x2 __attribute__((ext_vector_type(2)));
typedef __bf16    bf16x4 __attribute__((ext_vector_type(4)));
typedef __bf16    bf16x8 __attribute__((ext_vector_type(8)));
typedef _Float16  f16x4  __attribute__((ext_vector_type(4)));
typedef _Float16  f16x8  __attribute__((ext_vector_type(8)));
typedef float     f32x4  __attribute__((ext_vector_type(4)));
typedef float     f32x16 __attribute__((ext_vector_type(16)));
typedef uint32_t  u32x4  __attribute__((ext_vector_type(4)));

// async global->LDS, 16 B per lane. LDS dest = wave-uniform base + lane*16.
typedef const __attribute__((address_space(1))) uint32_t* gas_ptr;
typedef __attribute__((address_space(3))) uint32_t* las_ptr;
__device__ __forceinline__ void gl_lds16(const void* g, void* l) {
    __builtin_amdgcn_global_load_lds((gas_ptr)(uintptr_t)g,
                                     (las_ptr)(uintptr_t)l, 16, 0, 0);
}

// v_cvt_pk_bf16_f32: pack 2 f32 -> u32 of 2 bf16 (no builtin on gfx950, m240)
__device__ __forceinline__ uint32_t cvtpk_bf16(float lo, float hi) {
    uint32_t r;
    asm("v_cvt_pk_bf16_f32 %0, %1, %2" : "=v"(r) : "v"(lo), "v"(hi));
    return r;
}
// v_permlane32_swap_b32: a.hi <-> b.lo (VALU cross-lane, no LDS pipe)
__device__ __forceinline__ void plswap(uint32_t& a, uint32_t& b) {
    asm("v_permlane32_swap_b32 %0, %1" : "+v"(a), "+v"(b));
}

// ---------------------------------------------------------------------------
// prep kernel: region A = x fp32->fp16 (8192 blocks), region B = Wqkv
// transpose+cvt (768 blocks), region C = Wout transpose+cvt (256 blocks).
// ---------------------------------------------------------------------------
__global__ __launch_bounds__(256) void prep_kernel(
    const float* __restrict__ x, _Float16* __restrict__ x16,
    const float* __restrict__ Wqkv, _Float16* __restrict__ Wq16,
    const float* __restrict__ Wout, _Float16* __restrict__ Wo16)
{
    __shared__ float tile[64][65];
    int bid = blockIdx.x;
    const int tid = threadIdx.x;

    if (bid < 8192) {                      // cvt x
        int i = (bid * 256 + tid) * 4;
        float4 v = *(const float4*)&x[i];
        f16x4 o = {(_Float16)v.x, (_Float16)v.y, (_Float16)v.z, (_Float16)v.w};
        *(f16x4*)&x16[i] = o;
        return;
    }
    bid -= 8192;
    const float* W; _Float16* Wt; int N, tx, ty;
    if (bid < 768) { W = Wqkv; Wt = Wq16; N = 3072; tx = bid % 48; ty = bid / 48; }
    else { bid -= 768; W = Wout; Wt = Wo16; N = 1024; tx = bid % 16; ty = bid / 16; }
    const int K = 1024;
    const int k0 = ty * 64, n0 = tx * 64;
    for (int i = tid; i < 1024; i += 256) {
        int r = i >> 4, c4 = (i & 15) * 4;
        float4 v = *(const float4*)&W[(size_t)(k0 + r) * N + n0 + c4];
        tile[r][c4 + 0] = v.x; tile[r][c4 + 1] = v.y;
        tile[r][c4 + 2] = v.z; tile[r][c4 + 3] = v.w;
    }
    __syncthreads();
    for (int i = tid; i < 1024; i += 256) {
        int n = i >> 4, k4 = (i & 15) * 4;
        f16x4 o = {(_Float16)tile[k4 + 0][n], (_Float16)tile[k4 + 1][n],
                   (_Float16)tile[k4 + 2][n], (_Float16)tile[k4 + 3][n]};
        *(f16x4*)&Wt[(size_t)(n0 + n) * K + k0 + k4] = o;
    }
}

// ---------------------------------------------------------------------------
// fp16 MFMA GEMM — R10-verified structure (Bsh staging restored).
// R11 post-mortem: B-direct-from-global regressed (83->130 us): strided
// 16B-per-lane fragment loads are uncoalesced (64 cache lines/wave-load);
// LDS staging is a coalescing transform, not just a cache. Reverted.
// R11b change: MODE 0 (out-proj) BN 64 -> 128. NJ=2 had the worst
// LDS:MFMA ratio (6 reads per 8 MFMA = 1.86:1); BN=128 restores 1.24:1
// on the MODE-1-verified code path (pure constant flip).
//  - BK=64, XOR chunk-swizzle staging (R7/R8-proven): source k-chunk
//    (cc^rr), linear gl_lds dest, read at ((h*4+quad) ^ (row&7)).
// R9 lesson kept: no launch-bounds occupancy hints that squeeze VGPR.
// ---------------------------------------------------------------------------
template <int MODE>
__global__ __launch_bounds__(256) void gemm_f16_bt_kernel(
    const _Float16* __restrict__ A, const _Float16* __restrict__ Bt,
    const float* __restrict__ bias, void* __restrict__ Cout,
    __bf16* __restrict__ vTout, const float* __restrict__ q_gamma,
    const float* __restrict__ k_gamma, int M, int N, int K)
{
    constexpr int BN = 128;                      // cols per block (both modes)
    constexpr int NJ = BN / 32;                  // acc cols per wave (4)
    __shared__ __align__(16) char smraw[(128 + BN) * 64 * 2];
    _Float16* Ash = (_Float16*)smraw;
    _Float16* Bsh = Ash + 128 * 64;

    const int tid  = threadIdx.x;
    const int lane = tid & 63;
    const int wv   = tid >> 6;
    const int wm   = wv & 1, wn = wv >> 1;
    const int n16  = lane & 15, quad = lane >> 4;
    const int brow = blockIdx.y * 128;
    const int bcol = blockIdx.x * BN;

    // staging: 8 rows/call, 8 x 16B chunks/row; lane -> row rr = lane>>3,
    // chunk pos cc = lane&7, SOURCE chunk cc^rr (inverse swizzle).
    const int rr = lane >> 3;
    const int sw = ((lane & 7) ^ rr) * 8;        // source k-offset (elems)
    const _Float16* gA = A  + (size_t)(brow + wv * 32 + rr) * K + sw;
    const _Float16* gB = Bt + (size_t)(bcol + wv * (BN / 4) + rr) * K + sw;
    _Float16* lA = &Ash[(wv * 32) * 64];
    _Float16* lB = &Bsh[(wv * (BN / 4)) * 64];

    f32x4 acc[4][NJ] = {};

    for (int k0 = 0; k0 < K; k0 += 64) {
        #pragma unroll
        for (int t = 0; t < 4; t++)
            gl_lds16(gA + k0 + (size_t)t * 8 * K, lA + t * 8 * 64);
        #pragma unroll
        for (int t = 0; t < BN / 32; t++)
            gl_lds16(gB + k0 + (size_t)t * 8 * K, lB + t * 8 * 64);
        __syncthreads();

        #pragma unroll
        for (int h = 0; h < 2; h++) {
            f16x8 ar[4], br[NJ];
            #pragma unroll
            for (int t = 0; t < 4; t++) {
                const int row = wm * 64 + t * 16 + n16;
                ar[t] = *(const f16x8*)&Ash[row * 64 + (((h << 2) | quad) ^ (row & 7)) * 8];
            }
            #pragma unroll
            for (int j = 0; j < NJ; j++) {
                const int row = wn * (BN / 2) + j * 16 + n16;
                br[j] = *(const f16x8*)&Bsh[row * 64 + (((h << 2) | quad) ^ (row & 7)) * 8];
            }
            #pragma unroll
            for (int i = 0; i < 4; i++)
                #pragma unroll
                for (int j = 0; j < NJ; j++)
                    acc[i][j] = __builtin_amdgcn_mfma_f32_16x16x32_f16(
                        ar[i], br[j], acc[i][j], 0, 0, 0);
        }
        __syncthreads();
    }

    if (MODE == 0) {
        #pragma unroll
        for (int j = 0; j < NJ; j++) {
            const int col = bcol + wn * (BN / 2) + j * 16 + n16;
            const float bv = bias[col];
            #pragma unroll
            for (int i = 0; i < 4; i++) {
                const int row0 = brow + wm * 64 + i * 16 + quad * 4;
                #pragma unroll
                for (int r = 0; r < 4; r++)
                    ((float*)Cout)[(size_t)(row0 + r) * N + col] = acc[i][j][r] + bv;
            }
        }
        return;
    }

    // ---------------- MODE 1: fused QKV epilogue ----------------
    const int region = bcol >> 10;         // 0 = q, 1 = k, 2 = v
    float bj[4];
    #pragma unroll
    for (int j = 0; j < 4; j++) bj[j] = bias[bcol + wn * 64 + j * 16 + n16];

    if (region < 2) {
        const float* gamma = (region == 0) ? q_gamma : k_gamma;
        const float scl = (region == 0) ? 1.44269504f : 8.0f;  // log2e | sqrt(D)
        const int cb = (bcol & 1023) + wn * 64 + n16;          // head-local col
        float gj[4];
        #pragma unroll
        for (int j = 0; j < 4; j++) gj[j] = gamma[cb + j * 16];

        #pragma unroll
        for (int i = 0; i < 4; i++) {
            #pragma unroll
            for (int r = 0; r < 4; r++) {
                float v0 = acc[i][0][r] + bj[0];
                float v1 = acc[i][1][r] + bj[1];
                float v2 = acc[i][2][r] + bj[2];
                float v3 = acc[i][3][r] + bj[3];
                float ss = v0 * v0 + v1 * v1 + v2 * v2 + v3 * v3;
                ss += __shfl_xor(ss, 1, 64);
                ss += __shfl_xor(ss, 2, 64);
                ss += __shfl_xor(ss, 4, 64);
                ss += __shfl_xor(ss, 8, 64);
                const float sc = scl / fmaxf(sqrtf(ss), 1e-12f);
                const int row = brow + wm * 64 + i * 16 + quad * 4 + r;
                __bf16* op = (__bf16*)Cout + (size_t)row * 3072 + bcol + wn * 64 + n16;
                op[ 0] = (__bf16)(v0 * gj[0] * sc);
                op[16] = (__bf16)(v1 * gj[1] * sc);
                op[32] = (__bf16)(v2 * gj[2] * sc);
                op[48] = (__bf16)(v3 * gj[3] * sc);
            }
        }
    } else {
        // v region: bias + bf16, BAND transpose (4 x 32 tokens) via
        // [128][40] LDS (10240 B, aliased over staging), store vT[b][h][d][l].
        __bf16* LTb = (__bf16*)smraw;          // [col 0..127][rowb 0..31] s=40
        const int d    = tid >> 1;             // output row (head-d), 0..127
        const int head = ((bcol - 2048) >> 6) + (d >> 6);
        const size_t vb0 = (((size_t)((brow >> 11) * 16 + head)) * 64 + (d & 63)) * 2048
                           + (brow & 2047);
        #pragma unroll
        for (int p = 0; p < 4; p++) {
            if (wm == (p >> 1)) {
                #pragma unroll
                for (int ii = 0; ii < 2; ii++) {
                    const int i = (p & 1) * 2 + ii;
                    #pragma unroll
                    for (int j = 0; j < 4; j++) {
                        const int col  = wn * 64 + j * 16 + n16;
                        const int rowb = ii * 16 + quad * 4;
                        bf16x4 t4 = {(__bf16)(acc[i][j][0] + bj[j]),
                                     (__bf16)(acc[i][j][1] + bj[j]),
                                     (__bf16)(acc[i][j][2] + bj[j]),
                                     (__bf16)(acc[i][j][3] + bj[j])};
                        *(bf16x4*)&LTb[col * 40 + rowb] = t4;
                    }
                }
            }
            __syncthreads();
            #pragma unroll
            for (int s = 0; s < 2; s++) {
                const int chunk = (tid & 1) * 2 + s;
                *(bf16x8*)&vTout[vb0 + p * 32 + chunk * 8] =
                    *(const bf16x8*)&LTb[d * 40 + chunk * 8];
            }
            __syncthreads();
        }
    }
}

// ---------------------------------------------------------------------------
// MFMA flash attention v9 (unchanged from R10 — verified, out of top-5):
// 256-q blocks, 8 waves, 32x32x16 MFMA, fully in-register P.
// ---------------------------------------------------------------------------
__global__ __launch_bounds__(512, 4) void attn_mfma_kernel(
    const __bf16* __restrict__ qkv, const __bf16* __restrict__ vT,
    _Float16* __restrict__ h16)
{
    const int tid  = threadIdx.x;
    const int lane = tid & 63;
    const int wv   = tid >> 6;           // 0..7
    const int l31  = lane & 31;
    const int h    = lane >> 5;
    const int x7   = l31 & 7;
    const int qt = blockIdx.x & 7;       // 8 q-tiles of 256
    const int hh = (blockIdx.x >> 3) & 15;
    const int bb = blockIdx.x >> 7;
    const int q0 = qt * 256;
    const int bh = bb * 16 + hh;

    __shared__ __align__(16) __bf16 smem[4 * 4096];   // 32768 B
    __bf16* Kbuf = smem;                 // 2 x [64 tok][64 d], chunk-swizzled
    __bf16* Vbuf = smem + 2 * 4096;      // 2 x [64 d][64 tok], chunk-swizzled

    const __bf16* kbase = &qkv[(size_t)(bb * L_) * 3072 + 1024 + hh * 64];
    const __bf16* vbase = &vT[(size_t)bh * 64 * 2048];

    const int lr = lane >> 3;
    const int lc = (lane & 7) ^ lr;
    const __bf16* kpre = kbase + (size_t)(wv * 8 + lr) * 3072 + lc * 8;
    const __bf16* vpre = vbase + (size_t)(wv * 8 + lr) * 2048 + lc * 8;
    __bf16* kdst = Kbuf + (wv * 8) * 64;
    __bf16* vdst = Vbuf + (wv * 8) * 64;

    gl_lds16(kpre, kdst);
    gl_lds16(vpre, vdst);

    bf16x8 qf[4];
    const __bf16* qptr = &qkv[(size_t)(bb * L_ + q0 + wv * 32 + l31) * 3072
                              + hh * 64 + h * 8];
    #pragma unroll
    for (int dk = 0; dk < 4; dk++)
        qf[dk] = *(const bf16x8*)&qptr[dk * 16];

    f32x16 acc0 = {}, acc1 = {};
    float l_run = 0.f;

    __syncthreads();   // drains K[0], V[0]

    for (int j0 = 0, cur = 0; j0 < L_; j0 += 64, cur ^= 1) {
        if (j0 + 64 < L_) {
            gl_lds16(kpre + (size_t)(j0 + 64) * 3072, kdst + (cur ^ 1) * 4096);
            gl_lds16(vpre + (j0 + 64),                vdst + (cur ^ 1) * 4096);
        }
        const __bf16* Kc = Kbuf + cur * 4096;
        const __bf16* Vc = Vbuf + cur * 4096;

        f32x16 St0 = {}, St1 = {};
        __builtin_amdgcn_s_setprio(1);
        #pragma unroll
        for (int dk = 0; dk < 4; dk++) {
            const int co = ((2 * dk + h) ^ x7) * 8;
            bf16x8 k0 = *(const bf16x8*)&Kc[l31 * 64 + co];
            bf16x8 k1 = *(const bf16x8*)&Kc[(32 + l31) * 64 + co];
            St0 = __builtin_amdgcn_mfma_f32_32x32x16_bf16(k0, qf[dk], St0, 0, 0, 0);
            St1 = __builtin_amdgcn_mfma_f32_32x32x16_bf16(k1, qf[dk], St1, 0, 0, 0);
        }
        __builtin_amdgcn_s_setprio(0);

        bf16x8 pf[4];
        float ts = 0.f;
        #pragma unroll
        for (int th = 0; th < 2; th++) {
            float e[16];
            #pragma unroll
            for (int r = 0; r < 16; r++) {
                e[r] = __builtin_amdgcn_exp2f(th == 0 ? St0[r] : St1[r]);
                ts += e[r];
            }
            uint32_t a0 = cvtpk_bf16(e[0], e[1]),  a1 = cvtpk_bf16(e[2], e[3]);
            uint32_t b0 = cvtpk_bf16(e[4], e[5]),  b1 = cvtpk_bf16(e[6], e[7]);
            plswap(a0, b0); plswap(a1, b1);
            u32x4 w0; w0.x = a0; w0.y = a1; w0.z = b0; w0.w = b1;
            pf[th * 2 + 0] = __builtin_bit_cast(bf16x8, w0);
            uint32_t c0 = cvtpk_bf16(e[8], e[9]),   c1 = cvtpk_bf16(e[10], e[11]);
            uint32_t d0 = cvtpk_bf16(e[12], e[13]), d1 = cvtpk_bf16(e[14], e[15]);
            plswap(c0, d0); plswap(c1, d1);
            u32x4 w1; w1.x = c0; w1.y = c1; w1.z = d0; w1.w = d1;
            pf[th * 2 + 1] = __builtin_bit_cast(bf16x8, w1);
        }
        l_run += ts;

        __builtin_amdgcn_s_setprio(1);
        #pragma unroll
        for (int kq = 0; kq < 4; kq++) {
            const int co = ((2 * kq + h) ^ x7) * 8;
            bf16x8 v0 = *(const bf16x8*)&Vc[l31 * 64 + co];
            bf16x8 v1 = *(const bf16x8*)&Vc[(32 + l31) * 64 + co];
            acc0 = __builtin_amdgcn_mfma_f32_32x32x16_bf16(v0, pf[kq], acc0, 0, 0, 0);
            acc1 = __builtin_amdgcn_mfma_f32_32x32x16_bf16(v1, pf[kq], acc1, 0, 0, 0);
        }
        __builtin_amdgcn_s_setprio(0);

        __syncthreads();
    }

    l_run += __shfl_xor(l_run, 32, 64);
    const float linv = 1.0f / l_run;

    const size_t orow = (size_t)(bb * L_ + q0 + wv * 32 + l31) * 1024
                        + hh * 64 + h * 4;
    #pragma unroll
    for (int m = 0; m < 4; m++) {
        f16x4 o0 = {(_Float16)(acc0[4 * m + 0] * linv),
                    (_Float16)(acc0[4 * m + 1] * linv),
                    (_Float16)(acc0[4 * m + 2] * linv),
                    (_Float16)(acc0[4 * m + 3] * linv)};
        *(f16x4*)&h16[orow + 8 * m] = o0;
        f16x4 o1 = {(_Float16)(acc1[4 * m + 0] * linv),
                    (_Float16)(acc1[4 * m + 1] * linv),
                    (_Float16)(acc1[4 * m + 2] * linv),
                    (_Float16)(acc1[4 * m + 3] * linv)};
        *(f16x4*)&h16[orow + 32 + 8 * m] = o1;
    }
}

// ---------------------------------------------------------------------------
extern "C" void kernel_launch(void* const* d_in, const int* in_sizes, int n_in,
                              void* d_out, int out_size, void* d_ws, size_t ws_size,
                              hipStream_t stream)
{
    const float* x       = (const float*)d_in[0];
    const float* Wqkv    = (const float*)d_in[1];
    const float* bqkv    = (const float*)d_in[2];
    const float* q_gamma = (const float*)d_in[3];
    const float* k_gamma = (const float*)d_in[4];
    const float* Wout    = (const float*)d_in[5];
    const float* bout    = (const float*)d_in[6];
    float* out = (float*)d_out;

    uint8_t* ws = (uint8_t*)d_ws;
    _Float16* x16   = (_Float16*)(ws);                      // 16 MB
    _Float16* Wq16  = (_Float16*)(ws + (16ull << 20));      //  6 MB
    _Float16* Wo16  = (_Float16*)(ws + (22ull << 20));      //  2 MB
    __bf16*   qkv16 = (__bf16*)  (ws + (24ull << 20));      // 48 MB (q,k used)
    _Float16* h16   = (_Float16*)(ws + (72ull << 20));      // 16 MB
    __bf16*   vT    = (__bf16*)  (ws + (88ull << 20));      // 16 MB (total 104)

    // 1) prep: x->fp16, W transposes (one launch, 3 regions)
    prep_kernel<<<8192 + 768 + 256, 256, 0, stream>>>(x, x16, Wqkv, Wq16, Wout, Wo16);

    // 2) fused QKV: GEMM (BK=64, swizzled Bsh staging — R10-verified) + epilogues
    gemm_f16_bt_kernel<1><<<dim3(3 * C_ / 128, B_ * L_ / 128), 256, 0, stream>>>(
        x16, Wq16, bqkv, qkv16, vT, q_gamma, k_gamma, B_ * L_, 3 * C_, C_);

    // 3) flash attention (256-q blocks, 8 waves, 32x32 MFMA, in-reg P) -> h16
    attn_mfma_kernel<<<B_ * H_ * (L_ / 256), 512, 0, stream>>>(qkv16, vT, h16);

    // 4) out = h @ Wout + bout -> fp32 (128x128 tiles: NJ=4, best LDS ratio)
    gemm_f16_bt_kernel<0><<<dim3(C_ / 128, B_ * L_ / 128), 256, 0, stream>>>(
        h16, Wo16, bout, out, nullptr, nullptr, nullptr, B_ * L_, C_, C_);
}

// Round 13
// 270.152 us; speedup vs baseline: 1.2666x; 1.0250x over previous
//
#include <hip/hip_runtime.h>
#include <hip/hip_bf16.h>
#include <cstdint>
#include <cstddef>

#define B_ 4
#define L_ 2048
#define C_ 1024
#define H_ 16
#define D_ 64

typedef __bf16    bf16x2 __attribute__((ext_vector_type(2)));
typedef __bf16    bf16x4 __attribute__((ext_vector_type(4)));
typedef __bf16    bf16x8 __attribute__((ext_vector_type(8)));
typedef _Float16  f16x4  __attribute__((ext_vector_type(4)));
typedef _Float16  f16x8  __attribute__((ext_vector_type(8)));
typedef float     f32x4  __attribute__((ext_vector_type(4)));
typedef float     f32x16 __attribute__((ext_vector_type(16)));
typedef uint32_t  u32x4  __attribute__((ext_vector_type(4)));

// async global->LDS, 16 B per lane. LDS dest = wave-uniform base + lane*16.
typedef const __attribute__((address_space(1))) uint32_t* gas_ptr;
typedef __attribute__((address_space(3))) uint32_t* las_ptr;
__device__ __forceinline__ void gl_lds16(const void* g, void* l) {
    __builtin_amdgcn_global_load_lds((gas_ptr)(uintptr_t)g,
                                     (las_ptr)(uintptr_t)l, 16, 0, 0);
}

// v_cvt_pk_bf16_f32: pack 2 f32 -> u32 of 2 bf16 (no builtin on gfx950, m240)
__device__ __forceinline__ uint32_t cvtpk_bf16(float lo, float hi) {
    uint32_t r;
    asm("v_cvt_pk_bf16_f32 %0, %1, %2" : "=v"(r) : "v"(lo), "v"(hi));
    return r;
}
// v_permlane32_swap_b32: a.hi <-> b.lo (VALU cross-lane, no LDS pipe)
__device__ __forceinline__ void plswap(uint32_t& a, uint32_t& b) {
    asm("v_permlane32_swap_b32 %0, %1" : "+v"(a), "+v"(b));
}

// ---------------------------------------------------------------------------
// prep kernel: region A = x fp32->fp16 (8192 blocks), region B = Wqkv
// transpose+cvt (768 blocks), region C = Wout transpose+cvt (256 blocks).
// ---------------------------------------------------------------------------
__global__ __launch_bounds__(256) void prep_kernel(
    const float* __restrict__ x, _Float16* __restrict__ x16,
    const float* __restrict__ Wqkv, _Float16* __restrict__ Wq16,
    const float* __restrict__ Wout, _Float16* __restrict__ Wo16)
{
    __shared__ float tile[64][65];
    int bid = blockIdx.x;
    const int tid = threadIdx.x;

    if (bid < 8192) {                      // cvt x
        int i = (bid * 256 + tid) * 4;
        float4 v = *(const float4*)&x[i];
        f16x4 o = {(_Float16)v.x, (_Float16)v.y, (_Float16)v.z, (_Float16)v.w};
        *(f16x4*)&x16[i] = o;
        return;
    }
    bid -= 8192;
    const float* W; _Float16* Wt; int N, tx, ty;
    if (bid < 768) { W = Wqkv; Wt = Wq16; N = 3072; tx = bid % 48; ty = bid / 48; }
    else { bid -= 768; W = Wout; Wt = Wo16; N = 1024; tx = bid % 16; ty = bid / 16; }
    const int K = 1024;
    const int k0 = ty * 64, n0 = tx * 64;
    for (int i = tid; i < 1024; i += 256) {
        int r = i >> 4, c4 = (i & 15) * 4;
        float4 v = *(const float4*)&W[(size_t)(k0 + r) * N + n0 + c4];
        tile[r][c4 + 0] = v.x; tile[r][c4 + 1] = v.y;
        tile[r][c4 + 2] = v.z; tile[r][c4 + 3] = v.w;
    }
    __syncthreads();
    for (int i = tid; i < 1024; i += 256) {
        int n = i >> 4, k4 = (i & 15) * 4;
        f16x4 o = {(_Float16)tile[k4 + 0][n], (_Float16)tile[k4 + 1][n],
                   (_Float16)tile[k4 + 2][n], (_Float16)tile[k4 + 3][n]};
        *(f16x4*)&Wt[(size_t)(n0 + n) * K + k0 + k4] = o;
    }
}

// ---------------------------------------------------------------------------
// fp16 MFMA GEMM — R10-verified structure (Bsh staging), BN=128 both modes.
//  - BK=64, XOR chunk-swizzle staging (R7/R8-proven): source k-chunk
//    (cc^rr), linear gl_lds dest, read at ((h*4+quad) ^ (row&7)).
// R11 lesson: LDS staging is a coalescing transform — never replace with
// strided per-lane global fragment loads. R9 lesson: no launch-bounds
// occupancy hints that squeeze VGPR below the accumulator footprint.
// ---------------------------------------------------------------------------
template <int MODE>
__global__ __launch_bounds__(256) void gemm_f16_bt_kernel(
    const _Float16* __restrict__ A, const _Float16* __restrict__ Bt,
    const float* __restrict__ bias, void* __restrict__ Cout,
    __bf16* __restrict__ vTout, const float* __restrict__ q_gamma,
    const float* __restrict__ k_gamma, int M, int N, int K)
{
    constexpr int BN = 128;                      // cols per block (both modes)
    constexpr int NJ = BN / 32;                  // acc cols per wave (4)
    __shared__ __align__(16) char smraw[(128 + BN) * 64 * 2];
    _Float16* Ash = (_Float16*)smraw;
    _Float16* Bsh = Ash + 128 * 64;

    const int tid  = threadIdx.x;
    const int lane = tid & 63;
    const int wv   = tid >> 6;
    const int wm   = wv & 1, wn = wv >> 1;
    const int n16  = lane & 15, quad = lane >> 4;
    const int brow = blockIdx.y * 128;
    const int bcol = blockIdx.x * BN;

    // staging: 8 rows/call, 8 x 16B chunks/row; lane -> row rr = lane>>3,
    // chunk pos cc = lane&7, SOURCE chunk cc^rr (inverse swizzle).
    const int rr = lane >> 3;
    const int sw = ((lane & 7) ^ rr) * 8;        // source k-offset (elems)
    const _Float16* gA = A  + (size_t)(brow + wv * 32 + rr) * K + sw;
    const _Float16* gB = Bt + (size_t)(bcol + wv * (BN / 4) + rr) * K + sw;
    _Float16* lA = &Ash[(wv * 32) * 64];
    _Float16* lB = &Bsh[(wv * (BN / 4)) * 64];

    f32x4 acc[4][NJ] = {};

    for (int k0 = 0; k0 < K; k0 += 64) {
        #pragma unroll
        for (int t = 0; t < 4; t++)
            gl_lds16(gA + k0 + (size_t)t * 8 * K, lA + t * 8 * 64);
        #pragma unroll
        for (int t = 0; t < BN / 32; t++)
            gl_lds16(gB + k0 + (size_t)t * 8 * K, lB + t * 8 * 64);
        __syncthreads();

        #pragma unroll
        for (int h = 0; h < 2; h++) {
            f16x8 ar[4], br[NJ];
            #pragma unroll
            for (int t = 0; t < 4; t++) {
                const int row = wm * 64 + t * 16 + n16;
                ar[t] = *(const f16x8*)&Ash[row * 64 + (((h << 2) | quad) ^ (row & 7)) * 8];
            }
            #pragma unroll
            for (int j = 0; j < NJ; j++) {
                const int row = wn * (BN / 2) + j * 16 + n16;
                br[j] = *(const f16x8*)&Bsh[row * 64 + (((h << 2) | quad) ^ (row & 7)) * 8];
            }
            #pragma unroll
            for (int i = 0; i < 4; i++)
                #pragma unroll
                for (int j = 0; j < NJ; j++)
                    acc[i][j] = __builtin_amdgcn_mfma_f32_16x16x32_f16(
                        ar[i], br[j], acc[i][j], 0, 0, 0);
        }
        __syncthreads();
    }

    if (MODE == 0) {
        #pragma unroll
        for (int j = 0; j < NJ; j++) {
            const int col = bcol + wn * (BN / 2) + j * 16 + n16;
            const float bv = bias[col];
            #pragma unroll
            for (int i = 0; i < 4; i++) {
                const int row0 = brow + wm * 64 + i * 16 + quad * 4;
                #pragma unroll
                for (int r = 0; r < 4; r++)
                    ((float*)Cout)[(size_t)(row0 + r) * N + col] = acc[i][j][r] + bv;
            }
        }
        return;
    }

    // ---------------- MODE 1: fused QKV epilogue ----------------
    const int region = bcol >> 10;         // 0 = q, 1 = k, 2 = v
    float bj[4];
    #pragma unroll
    for (int j = 0; j < 4; j++) bj[j] = bias[bcol + wn * 64 + j * 16 + n16];

    if (region < 2) {
        const float* gamma = (region == 0) ? q_gamma : k_gamma;
        const float scl = (region == 0) ? 1.44269504f : 8.0f;  // log2e | sqrt(D)
        const int cb = (bcol & 1023) + wn * 64 + n16;          // head-local col
        float gj[4];
        #pragma unroll
        for (int j = 0; j < 4; j++) gj[j] = gamma[cb + j * 16];

        #pragma unroll
        for (int i = 0; i < 4; i++) {
            #pragma unroll
            for (int r = 0; r < 4; r++) {
                float v0 = acc[i][0][r] + bj[0];
                float v1 = acc[i][1][r] + bj[1];
                float v2 = acc[i][2][r] + bj[2];
                float v3 = acc[i][3][r] + bj[3];
                float ss = v0 * v0 + v1 * v1 + v2 * v2 + v3 * v3;
                ss += __shfl_xor(ss, 1, 64);
                ss += __shfl_xor(ss, 2, 64);
                ss += __shfl_xor(ss, 4, 64);
                ss += __shfl_xor(ss, 8, 64);
                const float sc = scl / fmaxf(sqrtf(ss), 1e-12f);
                const int row = brow + wm * 64 + i * 16 + quad * 4 + r;
                __bf16* op = (__bf16*)Cout + (size_t)row * 3072 + bcol + wn * 64 + n16;
                op[ 0] = (__bf16)(v0 * gj[0] * sc);
                op[16] = (__bf16)(v1 * gj[1] * sc);
                op[32] = (__bf16)(v2 * gj[2] * sc);
                op[48] = (__bf16)(v3 * gj[3] * sc);
            }
        }
    } else {
        // v region: bias + bf16, BAND transpose (4 x 32 tokens) via
        // [128][40] LDS (10240 B, aliased over staging), store vT[b][h][d][l].
        __bf16* LTb = (__bf16*)smraw;          // [col 0..127][rowb 0..31] s=40
        const int d    = tid >> 1;             // output row (head-d), 0..127
        const int head = ((bcol - 2048) >> 6) + (d >> 6);
        const size_t vb0 = (((size_t)((brow >> 11) * 16 + head)) * 64 + (d & 63)) * 2048
                           + (brow & 2047);
        #pragma unroll
        for (int p = 0; p < 4; p++) {
            if (wm == (p >> 1)) {
                #pragma unroll
                for (int ii = 0; ii < 2; ii++) {
                    const int i = (p & 1) * 2 + ii;
                    #pragma unroll
                    for (int j = 0; j < 4; j++) {
                        const int col  = wn * 64 + j * 16 + n16;
                        const int rowb = ii * 16 + quad * 4;
                        bf16x4 t4 = {(__bf16)(acc[i][j][0] + bj[j]),
                                     (__bf16)(acc[i][j][1] + bj[j]),
                                     (__bf16)(acc[i][j][2] + bj[j]),
                                     (__bf16)(acc[i][j][3] + bj[j])};
                        *(bf16x4*)&LTb[col * 40 + rowb] = t4;
                    }
                }
            }
            __syncthreads();
            #pragma unroll
            for (int s = 0; s < 2; s++) {
                const int chunk = (tid & 1) * 2 + s;
                *(bf16x8*)&vTout[vb0 + p * 32 + chunk * 8] =
                    *(const bf16x8*)&LTb[d * 40 + chunk * 8];
            }
            __syncthreads();
        }
    }
}

// ---------------------------------------------------------------------------
// MFMA flash attention v10: 256-q blocks, 8 waves, 32x32x16 MFMA,
// fully in-register P. R12 change: softmax denominator computed in the
// MATRIX pipe (T-catalog ones-row trick) instead of the VALU:
//   lacc = mfma(ones_row0_Afrag, pf[kq], lacc) -> lacc[0] (h=0 lanes)
//   = sum_k P[q][k], accumulated across all kq and tiles.
// Removes the 32-add ts chain + l_run accumulate per tile (~66 cy/tile of
// VALU, the busier pipe: VALUBusy 49 > MfmaUtil 39); adds 4 MFMA/tile on an
// independent accumulator chain. l is now the sum of the SAME bf16-rounded
// P values PV uses (self-consistent normalization).
// ---------------------------------------------------------------------------
__global__ __launch_bounds__(512, 4) void attn_mfma_kernel(
    const __bf16* __restrict__ qkv, const __bf16* __restrict__ vT,
    _Float16* __restrict__ h16)
{
    const int tid  = threadIdx.x;
    const int lane = tid & 63;
    const int wv   = tid >> 6;           // 0..7
    const int l31  = lane & 31;
    const int h    = lane >> 5;
    const int x7   = l31 & 7;
    const int qt = blockIdx.x & 7;       // 8 q-tiles of 256
    const int hh = (blockIdx.x >> 3) & 15;
    const int bb = blockIdx.x >> 7;
    const int q0 = qt * 256;
    const int bh = bb * 16 + hh;

    __shared__ __align__(16) __bf16 smem[4 * 4096];   // 32768 B
    __bf16* Kbuf = smem;                 // 2 x [64 tok][64 d], chunk-swizzled
    __bf16* Vbuf = smem + 2 * 4096;      // 2 x [64 d][64 tok], chunk-swizzled

    const __bf16* kbase = &qkv[(size_t)(bb * L_) * 3072 + 1024 + hh * 64];
    const __bf16* vbase = &vT[(size_t)bh * 64 * 2048];

    const int lr = lane >> 3;
    const int lc = (lane & 7) ^ lr;
    const __bf16* kpre = kbase + (size_t)(wv * 8 + lr) * 3072 + lc * 8;
    const __bf16* vpre = vbase + (size_t)(wv * 8 + lr) * 2048 + lc * 8;
    __bf16* kdst = Kbuf + (wv * 8) * 64;
    __bf16* vdst = Vbuf + (wv * 8) * 64;

    gl_lds16(kpre, kdst);
    gl_lds16(vpre, vdst);

    bf16x8 qf[4];
    const __bf16* qptr = &qkv[(size_t)(bb * L_ + q0 + wv * 32 + l31) * 3072
                              + hh * 64 + h * 8];
    #pragma unroll
    for (int dk = 0; dk < 4; dk++)
        qf[dk] = *(const bf16x8*)&qptr[dk * 16];

    // ones A-fragment: A[row=0][k] = 1 for all k, other rows 0.
    // 32x32x16 A layout: row = lane&31 (verified by the passing QK^T
    // kernel: D row = A row = token l31) -> lane l31==0 holds 1.0 x8.
    u32x4 ow;
    const uint32_t ov = (l31 == 0) ? 0x3F803F80u : 0u;   // 2 x bf16(1.0)
    ow.x = ov; ow.y = ov; ow.z = ov; ow.w = ov;
    const bf16x8 onesf = __builtin_bit_cast(bf16x8, ow);

    f32x16 acc0 = {}, acc1 = {}, lacc = {};

    __syncthreads();   // drains K[0], V[0]

    for (int j0 = 0, cur = 0; j0 < L_; j0 += 64, cur ^= 1) {
        if (j0 + 64 < L_) {
            gl_lds16(kpre + (size_t)(j0 + 64) * 3072, kdst + (cur ^ 1) * 4096);
            gl_lds16(vpre + (j0 + 64),                vdst + (cur ^ 1) * 4096);
        }
        const __bf16* Kc = Kbuf + cur * 4096;
        const __bf16* Vc = Vbuf + cur * 4096;

        f32x16 St0 = {}, St1 = {};
        __builtin_amdgcn_s_setprio(1);
        #pragma unroll
        for (int dk = 0; dk < 4; dk++) {
            const int co = ((2 * dk + h) ^ x7) * 8;
            bf16x8 k0 = *(const bf16x8*)&Kc[l31 * 64 + co];
            bf16x8 k1 = *(const bf16x8*)&Kc[(32 + l31) * 64 + co];
            St0 = __builtin_amdgcn_mfma_f32_32x32x16_bf16(k0, qf[dk], St0, 0, 0, 0);
            St1 = __builtin_amdgcn_mfma_f32_32x32x16_bf16(k1, qf[dk], St1, 0, 0, 0);
        }
        __builtin_amdgcn_s_setprio(0);

        // ---- softmax + in-register P (cvt_pk + permlane32_swap) ----
        bf16x8 pf[4];
        #pragma unroll
        for (int th = 0; th < 2; th++) {
            float e[16];
            #pragma unroll
            for (int r = 0; r < 16; r++)
                e[r] = __builtin_amdgcn_exp2f(th == 0 ? St0[r] : St1[r]);
            uint32_t a0 = cvtpk_bf16(e[0], e[1]),  a1 = cvtpk_bf16(e[2], e[3]);
            uint32_t b0 = cvtpk_bf16(e[4], e[5]),  b1 = cvtpk_bf16(e[6], e[7]);
            plswap(a0, b0); plswap(a1, b1);
            u32x4 w0; w0.x = a0; w0.y = a1; w0.z = b0; w0.w = b1;
            pf[th * 2 + 0] = __builtin_bit_cast(bf16x8, w0);
            uint32_t c0 = cvtpk_bf16(e[8], e[9]),   c1 = cvtpk_bf16(e[10], e[11]);
            uint32_t d0 = cvtpk_bf16(e[12], e[13]), d1 = cvtpk_bf16(e[14], e[15]);
            plswap(c0, d0); plswap(c1, d1);
            u32x4 w1; w1.x = c0; w1.y = c1; w1.z = d0; w1.w = d1;
            pf[th * 2 + 1] = __builtin_bit_cast(bf16x8, w1);
        }

        // ---- PV + denominator via ones-row MFMA ----
        __builtin_amdgcn_s_setprio(1);
        #pragma unroll
        for (int kq = 0; kq < 4; kq++) {
            const int co = ((2 * kq + h) ^ x7) * 8;
            bf16x8 v0 = *(const bf16x8*)&Vc[l31 * 64 + co];
            bf16x8 v1 = *(const bf16x8*)&Vc[(32 + l31) * 64 + co];
            acc0 = __builtin_amdgcn_mfma_f32_32x32x16_bf16(v0, pf[kq], acc0, 0, 0, 0);
            acc1 = __builtin_amdgcn_mfma_f32_32x32x16_bf16(v1, pf[kq], acc1, 0, 0, 0);
            lacc = __builtin_amdgcn_mfma_f32_32x32x16_bf16(onesf, pf[kq], lacc, 0, 0, 0);
        }
        __builtin_amdgcn_s_setprio(0);

        __syncthreads();
    }

    // lacc[0] = sum_k P (h=0 lanes; h=1 lanes hold row4 = 0) -> broadcast
    float l_run = lacc[0];
    l_run += __shfl_xor(l_run, 32, 64);
    const float linv = 1.0f / l_run;

    const size_t orow = (size_t)(bb * L_ + q0 + wv * 32 + l31) * 1024
                        + hh * 64 + h * 4;
    #pragma unroll
    for (int m = 0; m < 4; m++) {
        f16x4 o0 = {(_Float16)(acc0[4 * m + 0] * linv),
                    (_Float16)(acc0[4 * m + 1] * linv),
                    (_Float16)(acc0[4 * m + 2] * linv),
                    (_Float16)(acc0[4 * m + 3] * linv)};
        *(f16x4*)&h16[orow + 8 * m] = o0;
        f16x4 o1 = {(_Float16)(acc1[4 * m + 0] * linv),
                    (_Float16)(acc1[4 * m + 1] * linv),
                    (_Float16)(acc1[4 * m + 2] * linv),
                    (_Float16)(acc1[4 * m + 3] * linv)};
        *(f16x4*)&h16[orow + 32 + 8 * m] = o1;
    }
}

// ---------------------------------------------------------------------------
extern "C" void kernel_launch(void* const* d_in, const int* in_sizes, int n_in,
                              void* d_out, int out_size, void* d_ws, size_t ws_size,
                              hipStream_t stream)
{
    const float* x       = (const float*)d_in[0];
    const float* Wqkv    = (const float*)d_in[1];
    const float* bqkv    = (const float*)d_in[2];
    const float* q_gamma = (const float*)d_in[3];
    const float* k_gamma = (const float*)d_in[4];
    const float* Wout    = (const float*)d_in[5];
    const float* bout    = (const float*)d_in[6];
    float* out = (float*)d_out;

    uint8_t* ws = (uint8_t*)d_ws;
    _Float16* x16   = (_Float16*)(ws);                      // 16 MB
    _Float16* Wq16  = (_Float16*)(ws + (16ull << 20));      //  6 MB
    _Float16* Wo16  = (_Float16*)(ws + (22ull << 20));      //  2 MB
    __bf16*   qkv16 = (__bf16*)  (ws + (24ull << 20));      // 48 MB (q,k used)
    _Float16* h16   = (_Float16*)(ws + (72ull << 20));      // 16 MB
    __bf16*   vT    = (__bf16*)  (ws + (88ull << 20));      // 16 MB (total 104)

    // 1) prep: x->fp16, W transposes (one launch, 3 regions)
    prep_kernel<<<8192 + 768 + 256, 256, 0, stream>>>(x, x16, Wqkv, Wq16, Wout, Wo16);

    // 2) fused QKV: GEMM (BK=64, swizzled Bsh staging) + epilogues
    gemm_f16_bt_kernel<1><<<dim3(3 * C_ / 128, B_ * L_ / 128), 256, 0, stream>>>(
        x16, Wq16, bqkv, qkv16, vT, q_gamma, k_gamma, B_ * L_, 3 * C_, C_);

    // 3) flash attention (256-q blocks, 8 waves, in-reg P, MFMA denominator)
    attn_mfma_kernel<<<B_ * H_ * (L_ / 256), 512, 0, stream>>>(qkv16, vT, h16);

    // 4) out = h @ Wout + bout -> fp32 (128x128 tiles)
    gemm_f16_bt_kernel<0><<<dim3(C_ / 128, B_ * L_ / 128), 256, 0, stream>>>(
        h16, Wo16, bout, out, nullptr, nullptr, nullptr, B_ * L_, C_, C_);
}